// Round 2
// baseline (178.423 us; speedup 1.0000x reference)
//
#include <hip/hip_runtime.h>

#define RANK 16
#define N 512
#define BTILE 64
#define NBLK (N / BTILE)   // 8 b-tiles per a

__global__ __launch_bounds__(256) void parafac_kernel(
    const float* __restrict__ f0,
    const float* __restrict__ f1,
    const float* __restrict__ f2,
    float* __restrict__ out)
{
    __shared__ float p[BTILE][RANK];   // 4 KB

    const int blk = blockIdx.x;
    const int a  = blk / NBLK;
    const int b0 = (blk % NBLK) * BTILE;
    const int t  = threadIdx.x;

    // Stage p[bi][k] = f0[k][a] * f1[k][b0+bi]; 1024 entries, 4 per thread.
    {
        int idx = t * 4;
#pragma unroll
        for (int j = 0; j < 4; ++j) {
            const int bi = (idx + j) >> 4;   // /RANK
            const int k  = (idx + j) & 15;   // %RANK
            p[bi][k] = f0[k * N + a] * f1[k * N + b0 + bi];
        }
    }

    // f2 fragment resident in registers: 16 x float4 (64 VGPRs).
    const int lane_c = (t & 127) * 4;        // c offset, two waves cover full row
    float4 v[RANK];
#pragma unroll
    for (int k = 0; k < RANK; ++k)
        v[k] = *reinterpret_cast<const float4*>(&f2[k * N + lane_c]);

    __syncthreads();

    const int g = t >> 7;                    // wave-pair group: 0 -> even bi, 1 -> odd bi
    float* outbase = out + ((size_t)a * N + b0) * N + lane_c;

#pragma unroll 2
    for (int bi = g; bi < BTILE; bi += 2) {
        // Broadcast read of this bi's 16 rank-products (wave-uniform address).
        const float4* pv = reinterpret_cast<const float4*>(&p[bi][0]);
        float pk[RANK];
        *reinterpret_cast<float4*>(&pk[0])  = pv[0];
        *reinterpret_cast<float4*>(&pk[4])  = pv[1];
        *reinterpret_cast<float4*>(&pk[8])  = pv[2];
        *reinterpret_cast<float4*>(&pk[12]) = pv[3];

        float4 acc = make_float4(0.f, 0.f, 0.f, 0.f);
#pragma unroll
        for (int k = 0; k < RANK; ++k) {
            acc.x = fmaf(pk[k], v[k].x, acc.x);
            acc.y = fmaf(pk[k], v[k].y, acc.y);
            acc.z = fmaf(pk[k], v[k].z, acc.z);
            acc.w = fmaf(pk[k], v[k].w, acc.w);
        }
        *reinterpret_cast<float4*>(outbase + (size_t)bi * N) = acc;
    }
}

extern "C" void kernel_launch(void* const* d_in, const int* in_sizes, int n_in,
                              void* d_out, int out_size, void* d_ws, size_t ws_size,
                              hipStream_t stream) {
    const float* f0 = (const float*)d_in[0];
    const float* f1 = (const float*)d_in[1];
    const float* f2 = (const float*)d_in[2];
    float* out = (float*)d_out;

    dim3 grid(N * NBLK);   // 512 * 8 = 4096 blocks
    dim3 block(256);
    parafac_kernel<<<grid, block, 0, stream>>>(f0, f1, f2, out);
}

// Round 4
// 113.039 us; speedup vs baseline: 1.5784x; 1.5784x over previous
//
#include <hip/hip_runtime.h>

#define RANK 16
#define N 512
#define BTILE 64
#define NBLK (N / BTILE)   // 8 b-tiles per a

typedef float vfloat4 __attribute__((ext_vector_type(4)));

__global__ __launch_bounds__(256) void parafac_kernel(
    const float* __restrict__ f0,
    const float* __restrict__ f1,
    const float* __restrict__ f2,
    float* __restrict__ out)
{
    __shared__ float pt[RANK][BTILE];   // k-major rank products, 4 KB

    const int blk = blockIdx.x;
    const int a  = blk / NBLK;
    const int b0 = (blk % NBLK) * BTILE;
    const int t  = threadIdx.x;

    // Stage pt[k][bi] = f0[k][a] * f1[k][b0+bi].
    // 256 threads: 16 threads per k-row, float4 each -> one pass, no conflicts.
    {
        const int k  = t >> 4;           // 0..15
        const int bi = (t & 15) * 4;     // 0..60
        const float s = f0[k * N + a];
        const vfloat4 f1v = *reinterpret_cast<const vfloat4*>(&f1[k * N + b0 + bi]);
        vfloat4 r = s * f1v;
        *reinterpret_cast<vfloat4*>(&pt[k][bi]) = r;
    }

    // f2 fragment resident in registers: 16 x float4 (64 VGPRs).
    const int c4 = (t & 127) * 4;        // two waves cover the full c-row
    vfloat4 v[RANK];
#pragma unroll
    for (int k = 0; k < RANK; ++k)
        v[k] = *reinterpret_cast<const vfloat4*>(&f2[k * N + c4]);

    __syncthreads();

    const int g = t >> 7;                // 0: even b-quads, 1: odd b-quads
    float* outa = out + ((size_t)a * N + b0) * N + c4;

    // Each thread computes a 4(b) x 4(c) register tile per iteration:
    // 16 k-steps x 16 FMA from one broadcast ds_read_b128 + resident v[k].
#pragma unroll
    for (int it = 0; it < BTILE / 8; ++it) {
        const int bb = (g + it * 2) * 4; // b-quad base within tile
        vfloat4 acc0 = (vfloat4)(0.f);
        vfloat4 acc1 = (vfloat4)(0.f);
        vfloat4 acc2 = (vfloat4)(0.f);
        vfloat4 acc3 = (vfloat4)(0.f);
#pragma unroll
        for (int k = 0; k < RANK; ++k) {
            const vfloat4 pk = *reinterpret_cast<const vfloat4*>(&pt[k][bb]); // broadcast
            const vfloat4 vk = v[k];
            acc0 += pk.x * vk;
            acc1 += pk.y * vk;
            acc2 += pk.z * vk;
            acc3 += pk.w * vk;
        }
        // 4 back-to-back streaming stores (no reuse -> nontemporal).
        float* o = outa + (size_t)bb * N;
        __builtin_nontemporal_store(acc0, reinterpret_cast<vfloat4*>(o));
        __builtin_nontemporal_store(acc1, reinterpret_cast<vfloat4*>(o + N));
        __builtin_nontemporal_store(acc2, reinterpret_cast<vfloat4*>(o + 2 * N));
        __builtin_nontemporal_store(acc3, reinterpret_cast<vfloat4*>(o + 3 * N));
    }
}

extern "C" void kernel_launch(void* const* d_in, const int* in_sizes, int n_in,
                              void* d_out, int out_size, void* d_ws, size_t ws_size,
                              hipStream_t stream) {
    const float* f0 = (const float*)d_in[0];
    const float* f1 = (const float*)d_in[1];
    const float* f2 = (const float*)d_in[2];
    float* out = (float*)d_out;

    dim3 grid(N * NBLK);   // 4096 blocks
    dim3 block(256);
    parafac_kernel<<<grid, block, 0, stream>>>(f0, f1, f2, out);
}

// Round 5
// 112.536 us; speedup vs baseline: 1.5855x; 1.0045x over previous
//
#include <hip/hip_runtime.h>

#define RANK 16
#define N 512
#define BTILE 64
#define NBLK (N / BTILE)   // 8 b-tiles per a

typedef float vfloat4 __attribute__((ext_vector_type(4)));

__global__ __launch_bounds__(256) void parafac_kernel(
    const float* __restrict__ f0,
    const float* __restrict__ f1,
    const float* __restrict__ f2,
    float* __restrict__ out)
{
    __shared__ float pt[RANK][BTILE];   // k-major rank products, 4 KB

    const int blk = blockIdx.x;
    const int a  = blk / NBLK;
    const int b0 = (blk % NBLK) * BTILE;
    const int t  = threadIdx.x;

    // Stage pt[k][bi] = f0[k][a] * f1[k][b0+bi].
    // 256 threads: 16 threads per k-row, float4 each -> one pass, no conflicts.
    {
        const int k  = t >> 4;           // 0..15
        const int bi = (t & 15) * 4;     // 0..60
        const float s = f0[k * N + a];
        const vfloat4 f1v = *reinterpret_cast<const vfloat4*>(&f1[k * N + b0 + bi]);
        vfloat4 r = s * f1v;
        *reinterpret_cast<vfloat4*>(&pt[k][bi]) = r;
    }

    // f2 fragment resident in registers: 16 x float4 (64 VGPRs).
    const int c4 = (t & 127) * 4;        // two waves cover the full c-row
    vfloat4 v[RANK];
#pragma unroll
    for (int k = 0; k < RANK; ++k)
        v[k] = *reinterpret_cast<const vfloat4*>(&f2[k * N + c4]);

    __syncthreads();

    const int g = t >> 7;                // 0: even b-quads, 1: odd b-quads
    float* outa = out + ((size_t)a * N + b0) * N + c4;

    // Each thread computes a 4(b) x 4(c) register tile per iteration:
    // 16 k-steps x 16 FMA from one broadcast ds_read_b128 + resident v[k].
#pragma unroll
    for (int it = 0; it < BTILE / 8; ++it) {
        const int bb = (g + it * 2) * 4; // b-quad base within tile
        vfloat4 acc0 = (vfloat4)(0.f);
        vfloat4 acc1 = (vfloat4)(0.f);
        vfloat4 acc2 = (vfloat4)(0.f);
        vfloat4 acc3 = (vfloat4)(0.f);
#pragma unroll
        for (int k = 0; k < RANK; ++k) {
            const vfloat4 pk = *reinterpret_cast<const vfloat4*>(&pt[k][bb]); // broadcast
            const vfloat4 vk = v[k];
            acc0 += pk.x * vk;
            acc1 += pk.y * vk;
            acc2 += pk.z * vk;
            acc3 += pk.w * vk;
        }
        // 4 back-to-back plain streaming stores (A/B vs R4: nt removed).
        float* o = outa + (size_t)bb * N;
        *reinterpret_cast<vfloat4*>(o)         = acc0;
        *reinterpret_cast<vfloat4*>(o + N)     = acc1;
        *reinterpret_cast<vfloat4*>(o + 2 * N) = acc2;
        *reinterpret_cast<vfloat4*>(o + 3 * N) = acc3;
    }
}

extern "C" void kernel_launch(void* const* d_in, const int* in_sizes, int n_in,
                              void* d_out, int out_size, void* d_ws, size_t ws_size,
                              hipStream_t stream) {
    const float* f0 = (const float*)d_in[0];
    const float* f1 = (const float*)d_in[1];
    const float* f2 = (const float*)d_in[2];
    float* out = (float*)d_out;

    dim3 grid(N * NBLK);   // 4096 blocks
    dim3 block(256);
    parafac_kernel<<<grid, block, 0, stream>>>(f0, f1, f2, out);
}

// Round 6
// 102.635 us; speedup vs baseline: 1.7384x; 1.0965x over previous
//
#include <hip/hip_runtime.h>

#define RANK 16
#define N 512
#define BTILE 64
#define NBLK (N / BTILE)          // 8 b-tiles per a
#define NCHUNK (N * NBLK)         // 4096 (a, btile) chunks
#define CPB 4                     // chunks per block (consecutive -> 512 KB/block)
#define GRID (NCHUNK / CPB)       // 1024 blocks, all co-resident

typedef float vfloat4 __attribute__((ext_vector_type(4)));

__global__ __launch_bounds__(256) void parafac_kernel(
    const float* __restrict__ f0,
    const float* __restrict__ f1,
    const float* __restrict__ f2,
    float* __restrict__ out)
{
    __shared__ float pt[RANK][BTILE];   // k-major rank products, 4 KB

    const int t    = threadIdx.x;
    const int wave = t >> 6;            // 0..3
    const int lane = t & 63;
    // wave -> contiguous 32-row strip x c-half; monotone store addresses
    const int rbase = (wave >> 1) * 32;     // 0 or 32
    const int c4    = (wave & 1) * 256 + lane * 4;

    // f2 fragment resident in registers: 16 x float4 (64 VGPRs), loaded ONCE.
    vfloat4 v[RANK];
#pragma unroll
    for (int k = 0; k < RANK; ++k)
        v[k] = *reinterpret_cast<const vfloat4*>(&f2[k * N + c4]);

    // Staging indices (constant across chunks)
    const int sk  = t >> 4;             // 0..15
    const int sbi = (t & 15) * 4;       // 0..60

    for (int ci = 0; ci < CPB; ++ci) {
        const int cid = blockIdx.x * CPB + ci;   // consecutive output regions
        const int a   = cid / NBLK;
        const int b0  = (cid % NBLK) * BTILE;

        // Stage pt[k][bi] = f0[k][a] * f1[k][b0+bi]
        {
            const float s = f0[sk * N + a];
            const vfloat4 f1v = *reinterpret_cast<const vfloat4*>(&f1[sk * N + b0 + sbi]);
            *reinterpret_cast<vfloat4*>(&pt[sk][sbi]) = s * f1v;
        }
        __syncthreads();

        float* outa = out + ((size_t)a * N + b0) * N + c4;

        // 8 iterations x 4 rows, strictly ascending addresses per wave.
#pragma unroll
        for (int it = 0; it < 8; ++it) {
            const int bb = rbase + it * 4;
            vfloat4 acc0 = (vfloat4)(0.f);
            vfloat4 acc1 = (vfloat4)(0.f);
            vfloat4 acc2 = (vfloat4)(0.f);
            vfloat4 acc3 = (vfloat4)(0.f);
#pragma unroll
            for (int k = 0; k < RANK; ++k) {
                const vfloat4 pk = *reinterpret_cast<const vfloat4*>(&pt[k][bb]); // broadcast
                const vfloat4 vk = v[k];
                acc0 += pk.x * vk;
                acc1 += pk.y * vk;
                acc2 += pk.z * vk;
                acc3 += pk.w * vk;
            }
            float* o = outa + (size_t)bb * N;
            *reinterpret_cast<vfloat4*>(o)         = acc0;
            *reinterpret_cast<vfloat4*>(o + N)     = acc1;
            *reinterpret_cast<vfloat4*>(o + 2 * N) = acc2;
            *reinterpret_cast<vfloat4*>(o + 3 * N) = acc3;
        }
        __syncthreads();   // pt reused next chunk
    }
}

extern "C" void kernel_launch(void* const* d_in, const int* in_sizes, int n_in,
                              void* d_out, int out_size, void* d_ws, size_t ws_size,
                              hipStream_t stream) {
    const float* f0 = (const float*)d_in[0];
    const float* f1 = (const float*)d_in[1];
    const float* f2 = (const float*)d_in[2];
    float* out = (float*)d_out;

    dim3 grid(GRID);    // 1024 blocks
    dim3 block(256);
    parafac_kernel<<<grid, block, 0, stream>>>(f0, f1, f2, out);
}